// Round 8
// baseline (70.077 us; speedup 1.0000x reference)
//
#include <hip/hip_runtime.h>
#include <hip/hip_bf16.h>

// Problem constants (from reference setup_inputs)
#define B_N    4096      // batch
#define D_K    1024      // feature dim
#define MARGIN 0.3f
#define BIGM   1e5f

typedef __attribute__((ext_vector_type(8))) short short8;
typedef __attribute__((ext_vector_type(4))) float f32x4;

__device__ inline ushort f2bf(float f) {
    unsigned u = __float_as_uint(f);
    unsigned r = (u + 0x7fffu + ((u >> 16) & 1u)) >> 16;
    return (ushort)r;
}

__device__ inline void async16(const ushort* g, ushort* l) {
    __builtin_amdgcn_global_load_lds(
        (const __attribute__((address_space(1))) void*)g,
        (__attribute__((address_space(3))) void*)l,
        16, 0, 0);
}

// Fused prep: convert feat -> bf16 (blocks 0..4095) and lut[id] -> bf16
// (blocks 4096..8191), compute fp32 squared row norms, and init min/max bufs.
__global__ void prep_all(const float* __restrict__ feat,
                         const float* __restrict__ lut,
                         const int* __restrict__ id,
                         ushort* __restrict__ featB, ushort* __restrict__ oimB,
                         float* __restrict__ sq_a, float* __restrict__ sq_b,
                         int* __restrict__ maxb, int* __restrict__ minb) {
    int b = blockIdx.x;
    int t = threadIdx.x;                       // 256 threads, 4 floats each
    if (b < 16) {                              // 16*256 = 4096 entries
        int i = b * 256 + t;
        maxb[i] = 0;                           // 0.0f
        minb[i] = 0x7F800000;                  // +inf
    }
    const float* src; ushort* dst; float* sq;
    if (b < B_N) {
        src = feat + (size_t)b * D_K;
        dst = featB + (size_t)b * D_K;
        sq  = sq_a + b;
    } else {
        int row = b - B_N;
        src = lut + (size_t)id[row] * D_K;
        dst = oimB + (size_t)row * D_K;
        sq  = sq_b + row;
    }
    float4 v = ((const float4*)src)[t];
    float ss = v.x * v.x + v.y * v.y + v.z * v.z + v.w * v.w;
    ushort4 bb;
    bb.x = f2bf(v.x); bb.y = f2bf(v.y); bb.z = f2bf(v.z); bb.w = f2bf(v.w);
    ((ushort4*)dst)[t] = bb;

    int lane = t & 63, w = t >> 6;
    #pragma unroll
    for (int o = 1; o < 64; o <<= 1) ss += __shfl_xor(ss, o);
    __shared__ float red[4];
    if (lane == 0) red[w] = ss;
    __syncthreads();
    if (t == 0) *sq = red[0] + red[1] + red[2] + red[3];
}

// 256x256-tile bf16 MFMA GEMM — m201-style 4-phase/K-tile schedule.
// BK=64, 16 K-tiles. Quadrant order (0,0)->(1,0)->(1,1)->(0,1):
//   A-halves last read P2, B-halves last read P3.
// Stage slots (2 global_load_lds each): P1: (t+1)B0, P2: (t+1)B1 [other buf,
// always safe], P3: (t+2)A0, P4: (t+2)A1 [current buf — safe, A reads done
// by P2-end barrier]. One counted vmcnt(4) per tile at P4: exactly ensures
// tile t+1 fully landed, leaves (t+2)A0/A1 in flight (never over-drains).
// Per phase: {ds_reads, stage, barrier, lgkmcnt(0), setprio+16 MFMA, barrier}
// — ds_read latency hides under the barrier wait.
// Zero-conflict chunk-XOR swizzle (verified R4): chunk j at phys j^(row&7).
// 8 waves 2(M)x4(N); per-wave 128x64; LDS 128 KiB.
__global__ __launch_bounds__(512, 2)
void dist_kernel(const ushort* __restrict__ A, const ushort* __restrict__ Bm,
                 const float* __restrict__ sqa, const float* __restrict__ sqb,
                 const int* __restrict__ ids,
                 int* __restrict__ maxb, int* __restrict__ minb) {
    __shared__ ushort lA[2][16384];   // 32 KB x2: rows 0-255 x 64 (halves 0/1)
    __shared__ ushort lB[2][16384];

    const int t = threadIdx.x;
    const int lane = t & 63;
    const int wid = t >> 6;          // 8 waves
    const int wr = wid >> 2;         // 0..1 (M)
    const int wc = wid & 3;          // 0..3 (N)
    const int l15 = lane & 15;
    const int h = lane >> 4;

    // T1 XCD swizzle (256 blocks, bijective)
    const int bid = blockIdx.y * gridDim.x + blockIdx.x;
    const int swz = (bid & 7) * 32 + (bid >> 3);
    const int rb = swz >> 4, cb = swz & 15;

    // ---- staging source offsets (elements), q = 0..3 covers 256x64 tile.
    // Phys elem = q*4096 + t*8; row = elem>>6, chunk j = (elem>>3)&7;
    // source chunk = j ^ (row&7)  (inverse of read swizzle).
    uint aofs[4], bofs[4];
    #pragma unroll
    for (int q = 0; q < 4; q++) {
        int elem = q * 4096 + t * 8;
        int r = elem >> 6;
        int j = (elem >> 3) & 7;
        int col = (j ^ (r & 7)) << 3;
        aofs[q] = (uint)(rb * 256 + r) * D_K + col;
        bofs[q] = (uint)(cb * 256 + r) * D_K + col;
    }
    const int lds_wo = wid * 512;    // wave-uniform lane-block offset (elems)

    // ---- fragment read offsets, swizzled chunk per ks
    const int q7 = l15 & 7;
    const int xs0 = (h ^ q7) << 3;           // ks=0 chunk
    const int xs1 = ((h + 4) ^ q7) << 3;     // ks=1 chunk
    const int arow = (wr * 128 + l15) * 64;  // + mh*4096 + mf*1024
    const int brow = (wc * 64  + l15) * 64;  // + nh*2048 + nf*1024

    f32x4 acc[8][4] = {};
    short8 af0[4][2], af1[4][2], bf0[2][2], bf1[2][2];

#define STA(q, kk, sw) async16(A  + aofs[q] + (kk) * 64, &lA[sw][(q) * 4096 + lds_wo])
#define STB(q, kk, sw) async16(Bm + bofs[q] + (kk) * 64, &lB[sw][(q) * 4096 + lds_wo])
#define SBAR  __builtin_amdgcn_s_barrier()
#define SCHB  __builtin_amdgcn_sched_barrier(0)
#define LGKM0 asm volatile("s_waitcnt lgkmcnt(0)" ::: "memory")

    // ---- prologue: tile 0 complete + tile 1 A-halves (12 loads)
    STA(0, 0, 0); STA(1, 0, 0); STA(2, 0, 0); STA(3, 0, 0);
    STB(0, 0, 0); STB(1, 0, 0); STB(2, 0, 0); STB(3, 0, 0);
    STA(0, 1, 1); STA(1, 1, 1); STA(2, 1, 1); STA(3, 1, 1);
    asm volatile("s_waitcnt vmcnt(4)" ::: "memory");  // tile 0 landed
    SCHB; SBAR;

    for (int kt = 0; kt < 16; ++kt) {
        const int s = kt & 1;
        const ushort* rA = &lA[s][0];
        const ushort* rB = &lB[s][0];

        // ---------- P1: Q(mh0,nh0) ----------
        #pragma unroll
        for (int mf = 0; mf < 4; mf++) {
            af0[mf][0] = *(const short8*)(rA + arow + mf * 1024 + xs0);
            af0[mf][1] = *(const short8*)(rA + arow + mf * 1024 + xs1);
        }
        #pragma unroll
        for (int nf = 0; nf < 2; nf++) {
            bf0[nf][0] = *(const short8*)(rB + brow + nf * 1024 + xs0);
            bf0[nf][1] = *(const short8*)(rB + brow + nf * 1024 + xs1);
        }
        if (kt < 15) { STB(0, kt + 1, s ^ 1); STB(1, kt + 1, s ^ 1); }
        SCHB; SBAR; LGKM0; SCHB;
        __builtin_amdgcn_s_setprio(1);
        #pragma unroll
        for (int mf = 0; mf < 4; mf++)
            #pragma unroll
            for (int nf = 0; nf < 2; nf++) {
                acc[mf][nf] = __builtin_amdgcn_mfma_f32_16x16x32_bf16(
                    af0[mf][0], bf0[nf][0], acc[mf][nf], 0, 0, 0);
                acc[mf][nf] = __builtin_amdgcn_mfma_f32_16x16x32_bf16(
                    af0[mf][1], bf0[nf][1], acc[mf][nf], 0, 0, 0);
            }
        __builtin_amdgcn_s_setprio(0);
        SCHB; SBAR;

        // ---------- P2: Q(mh1,nh0) ----------
        #pragma unroll
        for (int mf = 0; mf < 4; mf++) {
            af1[mf][0] = *(const short8*)(rA + arow + 4096 + mf * 1024 + xs0);
            af1[mf][1] = *(const short8*)(rA + arow + 4096 + mf * 1024 + xs1);
        }
        if (kt < 15) { STB(2, kt + 1, s ^ 1); STB(3, kt + 1, s ^ 1); }
        SCHB; SBAR; LGKM0; SCHB;
        __builtin_amdgcn_s_setprio(1);
        #pragma unroll
        for (int mf = 0; mf < 4; mf++)
            #pragma unroll
            for (int nf = 0; nf < 2; nf++) {
                acc[4 + mf][nf] = __builtin_amdgcn_mfma_f32_16x16x32_bf16(
                    af1[mf][0], bf0[nf][0], acc[4 + mf][nf], 0, 0, 0);
                acc[4 + mf][nf] = __builtin_amdgcn_mfma_f32_16x16x32_bf16(
                    af1[mf][1], bf0[nf][1], acc[4 + mf][nf], 0, 0, 0);
            }
        __builtin_amdgcn_s_setprio(0);
        SCHB; SBAR;

        // ---------- P3: Q(mh1,nh1) ----------  (A reads done: stage t+2 A0)
        #pragma unroll
        for (int nf = 0; nf < 2; nf++) {
            bf1[nf][0] = *(const short8*)(rB + brow + 2048 + nf * 1024 + xs0);
            bf1[nf][1] = *(const short8*)(rB + brow + 2048 + nf * 1024 + xs1);
        }
        if (kt < 14) { STA(0, kt + 2, s); STA(1, kt + 2, s); }
        SCHB; SBAR; LGKM0; SCHB;
        __builtin_amdgcn_s_setprio(1);
        #pragma unroll
        for (int mf = 0; mf < 4; mf++)
            #pragma unroll
            for (int nf = 0; nf < 2; nf++) {
                acc[4 + mf][2 + nf] = __builtin_amdgcn_mfma_f32_16x16x32_bf16(
                    af1[mf][0], bf1[nf][0], acc[4 + mf][2 + nf], 0, 0, 0);
                acc[4 + mf][2 + nf] = __builtin_amdgcn_mfma_f32_16x16x32_bf16(
                    af1[mf][1], bf1[nf][1], acc[4 + mf][2 + nf], 0, 0, 0);
            }
        __builtin_amdgcn_s_setprio(0);
        SCHB; SBAR;

        // ---------- P4: Q(mh0,nh1) ----------  (stage t+2 A1; tile wait)
        if (kt < 14) { STA(2, kt + 2, s); STA(3, kt + 2, s); }
        if (kt <= 13)      asm volatile("s_waitcnt vmcnt(4)" ::: "memory");
        else if (kt == 14) asm volatile("s_waitcnt vmcnt(0)" ::: "memory");
        SCHB; SBAR; SCHB;
        __builtin_amdgcn_s_setprio(1);
        #pragma unroll
        for (int mf = 0; mf < 4; mf++)
            #pragma unroll
            for (int nf = 0; nf < 2; nf++) {
                acc[mf][2 + nf] = __builtin_amdgcn_mfma_f32_16x16x32_bf16(
                    af0[mf][0], bf1[nf][0], acc[mf][2 + nf], 0, 0, 0);
                acc[mf][2 + nf] = __builtin_amdgcn_mfma_f32_16x16x32_bf16(
                    af0[mf][1], bf1[nf][1], acc[mf][2 + nf], 0, 0, 0);
            }
        __builtin_amdgcn_s_setprio(0);
        SCHB; SBAR;
    }
#undef STA
#undef STB

    // Epilogue: dist + masks + per-row max/min over this block's 256 cols.
    int colg[4]; float sb[4]; int idb[4];
    #pragma unroll
    for (int n = 0; n < 4; n++) {
        int c = cb * 256 + wc * 64 + n * 16 + l15;
        colg[n] = c; sb[n] = sqb[c]; idb[n] = ids[c];
    }
    #pragma unroll
    for (int m = 0; m < 8; m++) {
        #pragma unroll
        for (int r = 0; r < 4; r++) {
            int row = rb * 256 + wr * 128 + m * 16 + h * 4 + r;
            float sa = sqa[row];
            int ida = ids[row];
            float mx = 0.0f, mn = 3.0e38f;
            #pragma unroll
            for (int n = 0; n < 4; n++) {
                float s2 = sa + sb[n] - 2.0f * acc[m][n][r];
                float d = sqrtf(fmaxf(s2, 0.0f) + 1e-12f);
                bool same = (ida == idb[n]);
                float pv = (same && (row != colg[n])) ? d : 0.0f;
                float nv = same ? d + BIGM : d;
                mx = fmaxf(mx, pv);
                mn = fminf(mn, nv);
            }
            #pragma unroll
            for (int o = 1; o < 16; o <<= 1) {
                mx = fmaxf(mx, __shfl_xor(mx, o));
                mn = fminf(mn, __shfl_xor(mn, o));
            }
            if (l15 == 0) {
                atomicMax(maxb + row, __float_as_int(mx));
                atomicMin(minb + row, __float_as_int(mn));
            }
        }
    }
}

__global__ void finalize_k(const int* __restrict__ maxb, const int* __restrict__ minb,
                           float* __restrict__ out) {
    int i = blockIdx.x * blockDim.x + threadIdx.x;
    if (i < B_N) {
        float z = __int_as_float(maxb[i]) - __int_as_float(minb[i]) + MARGIN;
        out[i] = fmaxf(z, 0.0f);
    }
}

extern "C" void kernel_launch(void* const* d_in, const int* in_sizes, int n_in,
                              void* d_out, int out_size, void* d_ws, size_t ws_size,
                              hipStream_t stream) {
    const float* feat = (const float*)d_in[0];
    const float* lut  = (const float*)d_in[1];
    const int*   id   = (const int*)d_in[2];
    float* out = (float*)d_out;

    // workspace layout
    char* ws = (char*)d_ws;
    ushort* featB = (ushort*)ws;                                  // 8 MiB
    ushort* oimB  = (ushort*)(ws + (size_t)B_N * D_K * 2);        // 8 MiB
    float*  sq_a  = (float*)(ws + (size_t)2 * B_N * D_K * 2);
    float*  sq_b  = sq_a + B_N;
    int*    maxb  = (int*)(sq_b + B_N);
    int*    minb  = maxb + B_N;

    prep_all<<<2 * B_N, 256, 0, stream>>>(feat, lut, id, featB, oimB,
                                          sq_a, sq_b, maxb, minb);

    dim3 grid(B_N / 256, B_N / 256);
    dist_kernel<<<grid, 512, 0, stream>>>(featB, oimB, sq_a, sq_b, id, maxb, minb);

    finalize_k<<<(B_N + 255) / 256, 256, 0, stream>>>(maxb, minb, out);
}

// Round 9
// 41.554 us; speedup vs baseline: 1.6864x; 1.6864x over previous
//
#include <hip/hip_runtime.h>
#include <hip/hip_bf16.h>

// Problem constants (from reference setup_inputs)
#define B_N    4096      // batch
#define D_K    1024      // feature dim
#define N_C    1024      // number of distinct ids (N_ID) = LUT rows used
#define MARGIN 0.3f
#define BIGM   1e5f

typedef __attribute__((ext_vector_type(8))) short short8;
typedef __attribute__((ext_vector_type(4))) float f32x4;

__device__ inline ushort f2bf(float f) {
    unsigned u = __float_as_uint(f);
    unsigned r = (u + 0x7fffu + ((u >> 16) & 1u)) >> 16;
    return (ushort)r;
}

__device__ inline void async16(const ushort* g, ushort* l) {
    __builtin_amdgcn_global_load_lds(
        (const __attribute__((address_space(1))) void*)g,
        (__attribute__((address_space(3))) void*)l,
        16, 0, 0);
}

// Zero/init the reduction buffers and the id histogram.
__global__ void init_k(int* __restrict__ maxb, int* __restrict__ minb,
                       int* __restrict__ cnt) {
    int i = blockIdx.x * 256 + threadIdx.x;      // grid 16 -> 4096
    maxb[i] = 0;                                 // 0.0f
    minb[i] = 0x7F800000;                        // +inf
    if (i < N_C) cnt[i] = 0;
}

// Convert feat rows (blocks 0..4095) and lut rows 0..1023 (blocks 4096..5119)
// to bf16, compute fp32 squared norms, and histogram the ids.
__global__ void prep_all(const float* __restrict__ feat,
                         const float* __restrict__ lut,
                         const int* __restrict__ id,
                         ushort* __restrict__ featB, ushort* __restrict__ lutB,
                         float* __restrict__ sq_a, float* __restrict__ sq_b,
                         int* __restrict__ cnt) {
    int b = blockIdx.x;
    int t = threadIdx.x;                       // 256 threads, 4 floats each
    const float* src; ushort* dst; float* sq;
    if (b < B_N) {
        src = feat + (size_t)b * D_K;
        dst = featB + (size_t)b * D_K;
        sq  = sq_a + b;
        if (t == 0) atomicAdd(cnt + id[b], 1);
    } else {
        int c = b - B_N;                       // 0..1023
        src = lut + (size_t)c * D_K;
        dst = lutB + (size_t)c * D_K;
        sq  = sq_b + c;
    }
    float4 v = ((const float4*)src)[t];
    float ss = v.x * v.x + v.y * v.y + v.z * v.z + v.w * v.w;
    ushort4 bb;
    bb.x = f2bf(v.x); bb.y = f2bf(v.y); bb.z = f2bf(v.z); bb.w = f2bf(v.w);
    ((ushort4*)dst)[t] = bb;

    int lane = t & 63, w = t >> 6;
    #pragma unroll
    for (int o = 1; o < 64; o <<= 1) ss += __shfl_xor(ss, o);
    __shared__ float red[4];
    if (lane == 0) red[w] = ss;
    __syncthreads();
    if (t == 0) *sq = red[0] + red[1] + red[2] + red[3];
}

// 128x128-tile bf16 MFMA GEMM over D = feat x lut[0:1024]^T (M=4096, N=1024,
// K=1024), R7's proven skeleton: BK=32, TRIPLE-buffered LDS (48 KB), counted
// vmcnt(2) per tile, zero-conflict row-pair XOR swizzle, setprio.
// Epilogue uses the id-structure: col c IS the id; positives = (c == id[row],
// cnt>=2), negatives = present cols (cnt>0) with c != id[row].
// 8 waves 2(M)x4(N); per-wave 64x32 via 4x2 frags of 16x16x32.
__global__ __launch_bounds__(512, 2)
void dist_kernel(const ushort* __restrict__ A, const ushort* __restrict__ Bm,
                 const float* __restrict__ sqa, const float* __restrict__ sqb,
                 const int* __restrict__ ids, const int* __restrict__ cnt,
                 int* __restrict__ maxb, int* __restrict__ minb) {
    __shared__ ushort lds_[3 * 8192];   // 3 bufs x (A 4096 + B 4096 elems)

    const int t = threadIdx.x;
    const int lane = t & 63;
    const int wid = t >> 6;          // 8 waves
    const int wr = wid >> 2;         // 0..1 (M)
    const int wc = wid & 3;          // 0..3 (N)
    const int l15 = lane & 15;
    const int h = lane >> 4;

    // T1 XCD swizzle: 256 blocks, XCD k gets swz k*32..k*32+31 =
    // row-tiles 4k..4k+3 x all 8 col-tiles (A slice 1 MB + B 2 MB < L2).
    const int bid = blockIdx.y * gridDim.x + blockIdx.x;   // gridDim.x = 8
    const int swz = (bid & 7) * 32 + (bid >> 3);
    const int rb = swz >> 3, cb = swz & 7;

    // ---- staging sources (1 async16 per operand per kt; 512thr x 16B = 4096
    // elems = one 128x32 tile). Phys elem p = t*8; line rp = p>>6,
    // slot' = (p>>3)&7; logical slot = slot' ^ (rp&7); r = rp*2 + (slot>>2);
    // chunk j = slot&3 -> source col j*8 (inverse of read swizzle).
    int p = t * 8;
    int rp = p >> 6;
    int sl = ((p >> 3) & 7) ^ (rp & 7);
    int rr = rp * 2 + (sl >> 2);
    int jj = sl & 3;
    const ushort* gA = A  + (size_t)(rb * 128 + rr) * D_K + jj * 8;
    const ushort* gB = Bm + (size_t)(cb * 128 + rr) * D_K + jj * 8;
    const int lds_wo = wid * 512;    // wave-uniform lane-block offset (elems)

    // ---- swizzled fragment read offsets (elements within a 4096 buffer)
    const int par = (l15 & 1) << 2;
    int offA[4], offB[2];
    {
        int a0 = (wr * 64 + l15) >> 1;
        #pragma unroll
        for (int mf = 0; mf < 4; mf++) {
            int line = a0 + mf * 8;
            offA[mf] = line * 64 + (((par | h) ^ (line & 7)) << 3);
        }
        int b0 = (wc * 32 + l15) >> 1;
        #pragma unroll
        for (int nf = 0; nf < 2; nf++) {
            int line = b0 + nf * 8;
            offB[nf] = line * 64 + (((par | h) ^ (line & 7)) << 3);
        }
    }

    f32x4 acc[4][2] = {};

    // ---- prologue: stage tiles 0 and 1 into bufs 0 and 1
    async16(gA,      lds_ + lds_wo);
    async16(gB,      lds_ + 4096 + lds_wo);
    async16(gA + 32, lds_ + 8192 + lds_wo);
    async16(gB + 32, lds_ + 8192 + 4096 + lds_wo);

    int s3 = 0, w3 = 2;
    for (int kt = 0; kt < 32; ++kt) {
        const ushort* sA = lds_ + s3 * 8192;
        const ushort* sB = sA + 4096;
        ushort* wbuf = lds_ + w3 * 8192;

        // tile kt resident (2 newest outstanding = tile kt+1's loads)
        if (kt < 31) asm volatile("s_waitcnt vmcnt(2)" ::: "memory");
        else         asm volatile("s_waitcnt vmcnt(0)" ::: "memory");
        __builtin_amdgcn_sched_barrier(0);
        __builtin_amdgcn_s_barrier();
        __builtin_amdgcn_sched_barrier(0);

        short8 afv[4], bfv[2];
        #pragma unroll
        for (int mf = 0; mf < 4; mf++)
            afv[mf] = *(const short8*)(sA + offA[mf]);
        #pragma unroll
        for (int nf = 0; nf < 2; nf++)
            bfv[nf] = *(const short8*)(sB + offB[nf]);
        if (kt < 30) {          // stage tile kt+2 into buffer w3 (not in use)
            async16(gA + (kt + 2) * 32, wbuf + lds_wo);
            async16(gB + (kt + 2) * 32, wbuf + 4096 + lds_wo);
        }
        asm volatile("s_waitcnt lgkmcnt(0)" ::: "memory");
        __builtin_amdgcn_sched_barrier(0);
        __builtin_amdgcn_s_setprio(1);
        #pragma unroll
        for (int mf = 0; mf < 4; mf++)
            #pragma unroll
            for (int nf = 0; nf < 2; nf++)
                acc[mf][nf] = __builtin_amdgcn_mfma_f32_16x16x32_bf16(
                    afv[mf], bfv[nf], acc[mf][nf], 0, 0, 0);
        __builtin_amdgcn_s_setprio(0);
        __builtin_amdgcn_sched_barrier(0);
        __builtin_amdgcn_s_barrier();   // reads done: kt+1 may DMA into s3

        s3 = (s3 == 2) ? 0 : s3 + 1;
        w3 = (w3 == 2) ? 0 : w3 + 1;
    }

    // Epilogue: col c IS the id. pos = (c==ida && cnt[c]>=2);
    // neg = (cnt[c]>0 && c!=ida). Per-row max/min over this block's 128 cols.
    int colg[2]; float sb2[2]; int c2[2];
    #pragma unroll
    for (int nf = 0; nf < 2; nf++) {
        int c = cb * 128 + wc * 32 + nf * 16 + l15;
        colg[nf] = c; sb2[nf] = sqb[c]; c2[nf] = cnt[c];
    }
    #pragma unroll
    for (int m = 0; m < 4; m++) {
        #pragma unroll
        for (int r = 0; r < 4; r++) {
            int row = rb * 128 + wr * 64 + m * 16 + h * 4 + r;
            float sa = sqa[row];
            int ida = ids[row];
            float mx = 0.0f, mn = 3.0e38f;
            #pragma unroll
            for (int nf = 0; nf < 2; nf++) {
                float s2 = sa + sb2[nf] - 2.0f * acc[m][nf][r];
                float d = sqrtf(fmaxf(s2, 0.0f) + 1e-12f);
                bool iseq = (colg[nf] == ida);
                float pv = (iseq && c2[nf] >= 2) ? d : 0.0f;
                float nv = (c2[nf] > 0 && !iseq) ? d : 3.0e38f;
                mx = fmaxf(mx, pv);
                mn = fminf(mn, nv);
            }
            #pragma unroll
            for (int o = 1; o < 16; o <<= 1) {
                mx = fmaxf(mx, __shfl_xor(mx, o));
                mn = fminf(mn, __shfl_xor(mn, o));
            }
            if (l15 == 0) {
                atomicMax(maxb + row, __float_as_int(mx));
                atomicMin(minb + row, __float_as_int(mn));
            }
        }
    }
}

__global__ void finalize_k(const int* __restrict__ maxb, const int* __restrict__ minb,
                           float* __restrict__ out) {
    int i = blockIdx.x * blockDim.x + threadIdx.x;
    if (i < B_N) {
        float z = __int_as_float(maxb[i]) - __int_as_float(minb[i]) + MARGIN;
        out[i] = fmaxf(z, 0.0f);
    }
}

extern "C" void kernel_launch(void* const* d_in, const int* in_sizes, int n_in,
                              void* d_out, int out_size, void* d_ws, size_t ws_size,
                              hipStream_t stream) {
    const float* feat = (const float*)d_in[0];
    const float* lut  = (const float*)d_in[1];
    const int*   id   = (const int*)d_in[2];
    float* out = (float*)d_out;

    // workspace layout
    char* ws = (char*)d_ws;
    ushort* featB = (ushort*)ws;                                   // 8 MiB
    ushort* lutB  = (ushort*)(ws + (size_t)B_N * D_K * 2);         // 2 MiB
    float*  sq_a  = (float*)(ws + (size_t)(B_N + N_C) * D_K * 2);
    float*  sq_b  = sq_a + B_N;
    int*    cnt   = (int*)(sq_b + N_C);
    int*    maxb  = cnt + N_C;
    int*    minb  = maxb + B_N;

    init_k<<<16, 256, 0, stream>>>(maxb, minb, cnt);
    prep_all<<<B_N + N_C, 256, 0, stream>>>(feat, lut, id, featB, lutB,
                                            sq_a, sq_b, cnt);

    dim3 grid(N_C / 128, B_N / 128);   // 8 x 32 = 256 blocks
    dist_kernel<<<grid, 512, 0, stream>>>(featB, lutB, sq_a, sq_b, id, cnt,
                                          maxb, minb);

    finalize_k<<<16, 256, 0, stream>>>(maxb, minb, out);
}

// Round 10
// 41.472 us; speedup vs baseline: 1.6897x; 1.0020x over previous
//
#include <hip/hip_runtime.h>
#include <hip/hip_bf16.h>

// Problem constants (from reference setup_inputs)
#define B_N    4096      // batch
#define D_K    1024      // feature dim
#define N_C    1024      // number of distinct ids (N_ID) = LUT rows used
#define MARGIN 0.3f
#define BIGM   1e5f

typedef __attribute__((ext_vector_type(8))) short short8;
typedef __attribute__((ext_vector_type(4))) float f32x4;

__device__ inline ushort f2bf(float f) {
    unsigned u = __float_as_uint(f);
    unsigned r = (u + 0x7fffu + ((u >> 16) & 1u)) >> 16;
    return (ushort)r;
}

__device__ inline void async16(const ushort* g, ushort* l) {
    __builtin_amdgcn_global_load_lds(
        (const __attribute__((address_space(1))) void*)g,
        (__attribute__((address_space(3))) void*)l,
        16, 0, 0);
}

// Zero/init the reduction buffers and the id histogram.
__global__ void init_k(int* __restrict__ maxb, int* __restrict__ minb,
                       int* __restrict__ cnt) {
    int i = blockIdx.x * 256 + threadIdx.x;      // grid 16 -> 4096
    maxb[i] = 0;                                 // 0.0f
    minb[i] = 0x7F800000;                        // +inf
    if (i < N_C) cnt[i] = 0;
}

// Convert feat rows (blocks 0..4095) and lut rows 0..1023 (blocks 4096..5119)
// to bf16, compute fp32 squared norms, and histogram the ids.
__global__ void prep_all(const float* __restrict__ feat,
                         const float* __restrict__ lut,
                         const int* __restrict__ id,
                         ushort* __restrict__ featB, ushort* __restrict__ lutB,
                         float* __restrict__ sq_a, float* __restrict__ sq_b,
                         int* __restrict__ cnt) {
    int b = blockIdx.x;
    int t = threadIdx.x;                       // 256 threads, 4 floats each
    const float* src; ushort* dst; float* sq;
    if (b < B_N) {
        src = feat + (size_t)b * D_K;
        dst = featB + (size_t)b * D_K;
        sq  = sq_a + b;
        if (t == 0) atomicAdd(cnt + id[b], 1);
    } else {
        int c = b - B_N;                       // 0..1023
        src = lut + (size_t)c * D_K;
        dst = lutB + (size_t)c * D_K;
        sq  = sq_b + c;
    }
    float4 v = ((const float4*)src)[t];
    float ss = v.x * v.x + v.y * v.y + v.z * v.z + v.w * v.w;
    ushort4 bb;
    bb.x = f2bf(v.x); bb.y = f2bf(v.y); bb.z = f2bf(v.z); bb.w = f2bf(v.w);
    ((ushort4*)dst)[t] = bb;

    int lane = t & 63, w = t >> 6;
    #pragma unroll
    for (int o = 1; o < 64; o <<= 1) ss += __shfl_xor(ss, o);
    __shared__ float red[4];
    if (lane == 0) red[w] = ss;
    __syncthreads();
    if (t == 0) *sq = red[0] + red[1] + red[2] + red[3];
}

// 128x128-tile bf16 MFMA GEMM over D = feat x lut[0:1024]^T (M=4096, N=1024,
// K=1024). DEEP 8-buffer LDS pipeline (128 KiB): 7-tile prefetch lead,
// counted vmcnt(12) steady state (= tiles kt+1..kt+7 in flight, 2 loads
// each), macro-unrolled decreasing tail. Stage issued after the WAR barrier,
// BEFORE the MFMA cluster (DMA issue overlaps compute). Zero-conflict
// row-pair XOR swizzle (verified 0 conflicts R7/R8). setprio around MFMA.
// 8 waves 2(M)x4(N); per-wave 64x32 via 4x2 frags of 16x16x32; BK=32.
__global__ __launch_bounds__(512, 2)
void dist_kernel(const ushort* __restrict__ A, const ushort* __restrict__ Bm,
                 const float* __restrict__ sqa, const float* __restrict__ sqb,
                 const int* __restrict__ ids, const int* __restrict__ cnt,
                 int* __restrict__ maxb, int* __restrict__ minb) {
    __shared__ ushort lds_[8 * 8192];   // 8 bufs x (A 4096 + B 4096 elems)

    const int t = threadIdx.x;
    const int lane = t & 63;
    const int wid = t >> 6;          // 8 waves
    const int wr = wid >> 2;         // 0..1 (M)
    const int wc = wid & 3;          // 0..3 (N)
    const int l15 = lane & 15;
    const int h = lane >> 4;

    // T1 XCD swizzle: 256 blocks -> XCD k owns row-tiles 4k..4k+3 x all 8
    // col-tiles (A slice 1 MB + B 2 MB < 4 MB L2).
    const int bid = blockIdx.y * gridDim.x + blockIdx.x;   // gridDim.x = 8
    const int swz = (bid & 7) * 32 + (bid >> 3);
    const int rb = swz >> 3, cb = swz & 7;

    // ---- staging sources (1 async16 per operand per kt; 512thr x 16B = one
    // 128x32 tile). Phys elem p = t*8; line rp = p>>6, slot' = (p>>3)&7;
    // logical slot = slot' ^ (rp&7); r = rp*2 + (slot>>2); chunk j = slot&3.
    int p = t * 8;
    int rp = p >> 6;
    int sl = ((p >> 3) & 7) ^ (rp & 7);
    int rr = rp * 2 + (sl >> 2);
    int jj = sl & 3;
    const ushort* gA = A  + (size_t)(rb * 128 + rr) * D_K + jj * 8;
    const ushort* gB = Bm + (size_t)(cb * 128 + rr) * D_K + jj * 8;
    const int lds_wo = wid * 512;    // wave-uniform lane-block offset (elems)

    // ---- swizzled fragment read offsets (elements within a 4096 buffer)
    const int par = (l15 & 1) << 2;
    int offA[4], offB[2];
    {
        int a0 = (wr * 64 + l15) >> 1;
        #pragma unroll
        for (int mf = 0; mf < 4; mf++) {
            int line = a0 + mf * 8;
            offA[mf] = line * 64 + (((par | h) ^ (line & 7)) << 3);
        }
        int b0 = (wc * 32 + l15) >> 1;
        #pragma unroll
        for (int nf = 0; nf < 2; nf++) {
            int line = b0 + nf * 8;
            offB[nf] = line * 64 + (((par | h) ^ (line & 7)) << 3);
        }
    }

    f32x4 acc[4][2] = {};

    // ---- prologue: stage tiles 0..6 into bufs 0..6 (14 loads in flight)
    #pragma unroll
    for (int kt0 = 0; kt0 < 7; kt0++) {
        ushort* base = lds_ + kt0 * 8192;
        async16(gA + kt0 * 32, base + lds_wo);
        async16(gB + kt0 * 32, base + 4096 + lds_wo);
    }

    // One K-iteration. VMLIT = allowed outstanding AFTER the wait:
    // steady state 12 (= tiles kt+1..kt+7), decreasing in the tail.
#define KITER(KT, VMLIT)                                                    \
    {                                                                       \
        const int sb_ = ((KT) & 7) * 8192;                                  \
        asm volatile("s_waitcnt vmcnt(" VMLIT ")" ::: "memory");            \
        __builtin_amdgcn_sched_barrier(0);                                  \
        __builtin_amdgcn_s_barrier();     /* RAW: tile KT visible */        \
        __builtin_amdgcn_sched_barrier(0);                                  \
        short8 afv[4], bfv[2];                                              \
        _Pragma("unroll") for (int mf = 0; mf < 4; mf++)                    \
            afv[mf] = *(const short8*)(lds_ + sb_ + offA[mf]);              \
        _Pragma("unroll") for (int nf = 0; nf < 2; nf++)                    \
            bfv[nf] = *(const short8*)(lds_ + sb_ + 4096 + offB[nf]);       \
        asm volatile("s_waitcnt lgkmcnt(0)" ::: "memory");                  \
        __builtin_amdgcn_sched_barrier(0);                                  \
        __builtin_amdgcn_s_barrier();     /* WAR: buf reads done */         \
        if ((KT) + 7 < 32) {              /* stage tile KT+7 (overlaps MFMA) */ \
            ushort* wb_ = lds_ + (((KT) + 7) & 7) * 8192;                   \
            async16(gA + ((KT) + 7) * 32, wb_ + lds_wo);                    \
            async16(gB + ((KT) + 7) * 32, wb_ + 4096 + lds_wo);             \
        }                                                                   \
        __builtin_amdgcn_s_setprio(1);                                      \
        _Pragma("unroll") for (int mf = 0; mf < 4; mf++)                    \
            _Pragma("unroll") for (int nf = 0; nf < 2; nf++)                \
                acc[mf][nf] = __builtin_amdgcn_mfma_f32_16x16x32_bf16(      \
                    afv[mf], bfv[nf], acc[mf][nf], 0, 0, 0);                \
        __builtin_amdgcn_s_setprio(0);                                      \
        __builtin_amdgcn_sched_barrier(0);                                  \
    }

    for (int kt = 0; kt < 26; ++kt) KITER(kt, "12");
    KITER(26, "10");
    KITER(27, "8");
    KITER(28, "6");
    KITER(29, "4");
    KITER(30, "2");
    KITER(31, "0");
#undef KITER

    // Epilogue: col c IS the id. pos = (c==ida && cnt[c]>=2);
    // neg = (cnt[c]>0 && c!=ida). Per-row max/min over this block's 128 cols.
    int colg[2]; float sb2[2]; int c2[2];
    #pragma unroll
    for (int nf = 0; nf < 2; nf++) {
        int c = cb * 128 + wc * 32 + nf * 16 + l15;
        colg[nf] = c; sb2[nf] = sqb[c]; c2[nf] = cnt[c];
    }
    #pragma unroll
    for (int m = 0; m < 4; m++) {
        #pragma unroll
        for (int r = 0; r < 4; r++) {
            int row = rb * 128 + wr * 64 + m * 16 + h * 4 + r;
            float sa = sqa[row];
            int ida = ids[row];
            float mx = 0.0f, mn = 3.0e38f;
            #pragma unroll
            for (int nf = 0; nf < 2; nf++) {
                float s2 = sa + sb2[nf] - 2.0f * acc[m][nf][r];
                float d = sqrtf(fmaxf(s2, 0.0f) + 1e-12f);
                bool iseq = (colg[nf] == ida);
                float pv = (iseq && c2[nf] >= 2) ? d : 0.0f;
                float nv = (c2[nf] > 0 && !iseq) ? d : 3.0e38f;
                mx = fmaxf(mx, pv);
                mn = fminf(mn, nv);
            }
            #pragma unroll
            for (int o = 1; o < 16; o <<= 1) {
                mx = fmaxf(mx, __shfl_xor(mx, o));
                mn = fminf(mn, __shfl_xor(mn, o));
            }
            if (l15 == 0) {
                atomicMax(maxb + row, __float_as_int(mx));
                atomicMin(minb + row, __float_as_int(mn));
            }
        }
    }
}

__global__ void finalize_k(const int* __restrict__ maxb, const int* __restrict__ minb,
                           float* __restrict__ out) {
    int i = blockIdx.x * blockDim.x + threadIdx.x;
    if (i < B_N) {
        float z = __int_as_float(maxb[i]) - __int_as_float(minb[i]) + MARGIN;
        out[i] = fmaxf(z, 0.0f);
    }
}

extern "C" void kernel_launch(void* const* d_in, const int* in_sizes, int n_in,
                              void* d_out, int out_size, void* d_ws, size_t ws_size,
                              hipStream_t stream) {
    const float* feat = (const float*)d_in[0];
    const float* lut  = (const float*)d_in[1];
    const int*   id   = (const int*)d_in[2];
    float* out = (float*)d_out;

    // workspace layout
    char* ws = (char*)d_ws;
    ushort* featB = (ushort*)ws;                                   // 8 MiB
    ushort* lutB  = (ushort*)(ws + (size_t)B_N * D_K * 2);         // 2 MiB
    float*  sq_a  = (float*)(ws + (size_t)(B_N + N_C) * D_K * 2);
    float*  sq_b  = sq_a + B_N;
    int*    cnt   = (int*)(sq_b + N_C);
    int*    maxb  = cnt + N_C;
    int*    minb  = maxb + B_N;

    init_k<<<16, 256, 0, stream>>>(maxb, minb, cnt);
    prep_all<<<B_N + N_C, 256, 0, stream>>>(feat, lut, id, featB, lutB,
                                            sq_a, sq_b, cnt);

    dim3 grid(N_C / 128, B_N / 128);   // 8 x 32 = 256 blocks
    dist_kernel<<<grid, 512, 0, stream>>>(featB, lutB, sq_a, sq_b, id, cnt,
                                          maxb, minb);

    finalize_k<<<16, 256, 0, stream>>>(maxb, minb, out);
}

// Round 12
// 39.458 us; speedup vs baseline: 1.7760x; 1.0510x over previous
//
#include <hip/hip_runtime.h>
#include <hip/hip_bf16.h>

// Problem constants (from reference setup_inputs)
#define B_N    4096      // batch
#define D_K    1024      // feature dim
#define N_C    1024      // number of distinct ids (N_ID) = LUT rows used
#define MARGIN 0.3f
#define BIGM   1e5f

typedef __attribute__((ext_vector_type(8))) short short8;
typedef __attribute__((ext_vector_type(4))) float f32x4;

__device__ inline ushort f2bf(float f) {
    unsigned u = __float_as_uint(f);
    unsigned r = (u + 0x7fffu + ((u >> 16) & 1u)) >> 16;
    return (ushort)r;
}

__device__ inline void async16(const ushort* g, ushort* l) {
    __builtin_amdgcn_global_load_lds(
        (const __attribute__((address_space(1))) void*)g,
        (__attribute__((address_space(3))) void*)l,
        16, 0, 0);
}

// Fused prep:
//  blocks 0..4095: feat rows -> bf16 + norms (first 16 also init maxb/minb)
//  blocks 4096..5119: lut rows 0..1023 -> bf16 + norms
//  block 5120: id histogram via LDS (no global atomics)
__global__ void prep_all(const float* __restrict__ feat,
                         const float* __restrict__ lut,
                         const int* __restrict__ id,
                         ushort* __restrict__ featB, ushort* __restrict__ lutB,
                         float* __restrict__ sq_a, float* __restrict__ sq_b,
                         int* __restrict__ cnt,
                         int* __restrict__ maxb, int* __restrict__ minb) {
    int b = blockIdx.x;
    int t = threadIdx.x;                       // 256 threads

    if (b == B_N + N_C) {                      // histogram block
        __shared__ int hc[N_C];
        #pragma unroll
        for (int i = 0; i < 4; i++) hc[t * 4 + i] = 0;
        __syncthreads();
        #pragma unroll
        for (int i = 0; i < 16; i++) atomicAdd(&hc[id[t * 16 + i]], 1);
        __syncthreads();
        #pragma unroll
        for (int i = 0; i < 4; i++) cnt[t * 4 + i] = hc[t * 4 + i];
        return;
    }

    if (b < 16) {                              // 16*256 = 4096 entries
        int i = b * 256 + t;
        maxb[i] = 0;                           // 0.0f
        minb[i] = 0x7F800000;                  // +inf
    }
    const float* src; ushort* dst; float* sq;
    if (b < B_N) {
        src = feat + (size_t)b * D_K;
        dst = featB + (size_t)b * D_K;
        sq  = sq_a + b;
    } else {
        int c = b - B_N;                       // 0..1023
        src = lut + (size_t)c * D_K;
        dst = lutB + (size_t)c * D_K;
        sq  = sq_b + c;
    }
    float4 v = ((const float4*)src)[t];
    float ss = v.x * v.x + v.y * v.y + v.z * v.z + v.w * v.w;
    ushort4 bb;
    bb.x = f2bf(v.x); bb.y = f2bf(v.y); bb.z = f2bf(v.z); bb.w = f2bf(v.w);
    ((ushort4*)dst)[t] = bb;

    int lane = t & 63, w = t >> 6;
    #pragma unroll
    for (int o = 1; o < 64; o <<= 1) ss += __shfl_xor(ss, o);
    __shared__ float red[4];
    if (lane == 0) red[w] = ss;
    __syncthreads();
    if (t == 0) *sq = red[0] + red[1] + red[2] + red[3];
}

// 64x64-tile bf16 MFMA GEMM over D = feat x lut[0:1024]^T (M=4096, N=1024,
// K=1024). SMALL blocks for cross-block TLP: 256 thr / 4 waves, 16 KB
// double-buffered LDS -> 4 blocks/CU; grid 1024. Counted vmcnt(2) (only
// 2 staging loads per K-tile). Zero-conflict row-pair XOR swizzle.
// NOTE (R11 bug fix): global_load_lds LDS dest must be wave-uniform base +
// wid*512 elems — all staging calls now carry "+ wo".
__global__ __launch_bounds__(256, 4)
void dist_kernel(const ushort* __restrict__ A, const ushort* __restrict__ Bm,
                 const float* __restrict__ sqa, const float* __restrict__ sqb,
                 const int* __restrict__ ids, const int* __restrict__ cnt,
                 int* __restrict__ maxb, int* __restrict__ minb) {
    __shared__ ushort lds_[2 * 4096];   // 2 bufs x (A 2048 + B 2048 elems)

    const int t = threadIdx.x;
    const int lane = t & 63;
    const int wid = t >> 6;          // 4 waves: 2(M) x 2(N)
    const int wr = wid >> 1;
    const int wc = wid & 1;
    const int l15 = lane & 15;
    const int h = lane >> 4;
    const int wo = wid * 512;        // per-wave LDS staging offset (elems)

    // T1 XCD swizzle: 1024 blocks -> XCD k owns row-tiles 8k..8k+7 x all 16
    // col-tiles (A-band 512 rows = 1 MB + B 2 MB < 4 MB L2).
    const int bid = blockIdx.y * gridDim.x + blockIdx.x;   // gridDim.x = 16
    const int swz = (bid & 7) * 128 + (bid >> 3);
    const int rb = swz >> 4, cb = swz & 15;

    // ---- staging source (1 async16 per operand per kt; 256thr x 16B = one
    // 64x32 tile = 2048 elems). Phys elem p = t*8; line rp = p>>6 (0..31),
    // slot' = (p>>3)&7; logical slot = slot' ^ (rp&7);
    // row r = rp*2 + (slot>>2); chunk j = slot&3 -> source col j*8.
    int p = t * 8;
    int rp = p >> 6;
    int sl = ((p >> 3) & 7) ^ (rp & 7);
    int rr = rp * 2 + (sl >> 2);
    int jj = sl & 3;
    const ushort* gA = A  + (size_t)(rb * 64 + rr) * D_K + jj * 8;
    const ushort* gB = Bm + (size_t)(cb * 64 + rr) * D_K + jj * 8;

    // ---- swizzled fragment read offsets (elements within a 2048 buffer)
    const int par = (l15 & 1) << 2;
    int offA[2], offB[2];
    {
        int a0 = (wr * 32 + l15) >> 1;
        #pragma unroll
        for (int mf = 0; mf < 2; mf++) {
            int line = a0 + mf * 8;
            offA[mf] = line * 64 + (((par | h) ^ (line & 7)) << 3);
        }
        int b0 = (wc * 32 + l15) >> 1;
        #pragma unroll
        for (int nf = 0; nf < 2; nf++) {
            int line = b0 + nf * 8;
            offB[nf] = line * 64 + (((par | h) ^ (line & 7)) << 3);
        }
    }

    f32x4 acc[2][2] = {};

    // ---- prologue: stage tile 0 into buf 0
    async16(gA, lds_ + wo);
    async16(gB, lds_ + 2048 + wo);

    for (int kt = 0; kt < 32; ++kt) {
        const int s = kt & 1;
        const ushort* sA = lds_ + s * 4096;
        const ushort* sB = sA + 2048;

        if (kt < 31) {       // stage kt+1 into other buf (read-done at kt-1)
            ushort* wb = lds_ + (s ^ 1) * 4096;
            async16(gA + (kt + 1) * 32, wb + wo);
            async16(gB + (kt + 1) * 32, wb + 2048 + wo);
            asm volatile("s_waitcnt vmcnt(2)" ::: "memory");  // kt landed
        } else {
            asm volatile("s_waitcnt vmcnt(0)" ::: "memory");
        }
        __builtin_amdgcn_sched_barrier(0);
        __builtin_amdgcn_s_barrier();        // RAW: tile kt visible
        __builtin_amdgcn_sched_barrier(0);

        short8 afv[2], bfv[2];
        #pragma unroll
        for (int mf = 0; mf < 2; mf++)
            afv[mf] = *(const short8*)(sA + offA[mf]);
        #pragma unroll
        for (int nf = 0; nf < 2; nf++)
            bfv[nf] = *(const short8*)(sB + offB[nf]);
        asm volatile("s_waitcnt lgkmcnt(0)" ::: "memory");
        __builtin_amdgcn_sched_barrier(0);
        __builtin_amdgcn_s_setprio(1);
        #pragma unroll
        for (int mf = 0; mf < 2; mf++)
            #pragma unroll
            for (int nf = 0; nf < 2; nf++)
                acc[mf][nf] = __builtin_amdgcn_mfma_f32_16x16x32_bf16(
                    afv[mf], bfv[nf], acc[mf][nf], 0, 0, 0);
        __builtin_amdgcn_s_setprio(0);
        __builtin_amdgcn_sched_barrier(0);
        __builtin_amdgcn_s_barrier();        // WAR: reads done before overwrite
    }

    // Epilogue: col c IS the id. pos = (c==ida && cnt[c]>=2);
    // neg = (cnt[c]>0 && c!=ida). Per-row max/min over this block's 64 cols.
    int colg[2]; float sb2[2]; int c2[2];
    #pragma unroll
    for (int nf = 0; nf < 2; nf++) {
        int c = cb * 64 + wc * 32 + nf * 16 + l15;
        colg[nf] = c; sb2[nf] = sqb[c]; c2[nf] = cnt[c];
    }
    #pragma unroll
    for (int m = 0; m < 2; m++) {
        #pragma unroll
        for (int r = 0; r < 4; r++) {
            int row = rb * 64 + wr * 32 + m * 16 + h * 4 + r;
            float sa = sqa[row];
            int ida = ids[row];
            float mx = 0.0f, mn = 3.0e38f;
            #pragma unroll
            for (int nf = 0; nf < 2; nf++) {
                float s2 = sa + sb2[nf] - 2.0f * acc[m][nf][r];
                float d = sqrtf(fmaxf(s2, 0.0f) + 1e-12f);
                bool iseq = (colg[nf] == ida);
                float pv = (iseq && c2[nf] >= 2) ? d : 0.0f;
                float nv = (c2[nf] > 0 && !iseq) ? d : 3.0e38f;
                mx = fmaxf(mx, pv);
                mn = fminf(mn, nv);
            }
            #pragma unroll
            for (int o = 1; o < 16; o <<= 1) {
                mx = fmaxf(mx, __shfl_xor(mx, o));
                mn = fminf(mn, __shfl_xor(mn, o));
            }
            if (l15 == 0) {
                atomicMax(maxb + row, __float_as_int(mx));
                atomicMin(minb + row, __float_as_int(mn));
            }
        }
    }
}

__global__ void finalize_k(const int* __restrict__ maxb, const int* __restrict__ minb,
                           float* __restrict__ out) {
    int i = blockIdx.x * blockDim.x + threadIdx.x;
    if (i < B_N) {
        float z = __int_as_float(maxb[i]) - __int_as_float(minb[i]) + MARGIN;
        out[i] = fmaxf(z, 0.0f);
    }
}

extern "C" void kernel_launch(void* const* d_in, const int* in_sizes, int n_in,
                              void* d_out, int out_size, void* d_ws, size_t ws_size,
                              hipStream_t stream) {
    const float* feat = (const float*)d_in[0];
    const float* lut  = (const float*)d_in[1];
    const int*   id   = (const int*)d_in[2];
    float* out = (float*)d_out;

    // workspace layout
    char* ws = (char*)d_ws;
    ushort* featB = (ushort*)ws;                                   // 8 MiB
    ushort* lutB  = (ushort*)(ws + (size_t)B_N * D_K * 2);         // 2 MiB
    float*  sq_a  = (float*)(ws + (size_t)(B_N + N_C) * D_K * 2);
    float*  sq_b  = sq_a + B_N;
    int*    cnt   = (int*)(sq_b + N_C);
    int*    maxb  = cnt + N_C;
    int*    minb  = maxb + B_N;

    prep_all<<<B_N + N_C + 1, 256, 0, stream>>>(feat, lut, id, featB, lutB,
                                                sq_a, sq_b, cnt, maxb, minb);

    dim3 grid(N_C / 64, B_N / 64);     // 16 x 64 = 1024 blocks
    dist_kernel<<<grid, 256, 0, stream>>>(featB, lutB, sq_a, sq_b, id, cnt,
                                          maxb, minb);

    finalize_k<<<16, 256, 0, stream>>>(maxb, minb, out);
}

// Round 13
// 38.811 us; speedup vs baseline: 1.8056x; 1.0167x over previous
//
#include <hip/hip_runtime.h>
#include <hip/hip_bf16.h>

// Problem constants (from reference setup_inputs)
#define B_N    4096      // batch
#define D_K    1024      // feature dim
#define N_C    1024      // number of distinct ids (N_ID) = LUT rows used
#define MARGIN 0.3f

typedef __attribute__((ext_vector_type(8))) short short8;
typedef __attribute__((ext_vector_type(4))) float f32x4;

__device__ inline ushort f2bf(float f) {
    unsigned u = __float_as_uint(f);
    unsigned r = (u + 0x7fffu + ((u >> 16) & 1u)) >> 16;
    return (ushort)r;
}

__device__ inline void async16(const ushort* g, ushort* l) {
    __builtin_amdgcn_global_load_lds(
        (const __attribute__((address_space(1))) void*)g,
        (__attribute__((address_space(3))) void*)l,
        16, 0, 0);
}

// Fused prep:
//  blocks 0..4095: feat row b -> bf16 PACKED fragment panels featP + sq_a.
//    Panel layout: group g = row>>4 (16 rows), per (g, kt): 1 KB block in
//    MFMA A-frag lane order: chunk index (row&15) + 16*h holds cols
//    kt*32 + h*8 .. +7.  -> dist loads A frags with ONE coalesced
//    16B/lane global load (no LDS for A).
//  blocks 4096..5119: lut rows -> bf16 row-major lutB + sq_b (DMA-staged).
//  block 5120: id histogram via LDS. First 16 blocks also init maxb/minb.
__global__ void prep_all(const float* __restrict__ feat,
                         const float* __restrict__ lut,
                         const int* __restrict__ id,
                         ushort* __restrict__ featP, ushort* __restrict__ lutB,
                         float* __restrict__ sq_a, float* __restrict__ sq_b,
                         int* __restrict__ cnt,
                         int* __restrict__ maxb, int* __restrict__ minb) {
    int b = blockIdx.x;
    int t = threadIdx.x;                       // 256 threads

    if (b == B_N + N_C) {                      // histogram block
        __shared__ int hc[N_C];
        #pragma unroll
        for (int i = 0; i < 4; i++) hc[t * 4 + i] = 0;
        __syncthreads();
        #pragma unroll
        for (int i = 0; i < 16; i++) atomicAdd(&hc[id[t * 16 + i]], 1);
        __syncthreads();
        #pragma unroll
        for (int i = 0; i < 4; i++) cnt[t * 4 + i] = hc[t * 4 + i];
        return;
    }

    if (b < 16) {                              // 16*256 = 4096 entries
        int i = b * 256 + t;
        maxb[i] = 0;                           // 0.0f
        minb[i] = 0x7F800000;                  // +inf
    }
    const float* src; float* sq;
    if (b < B_N) { src = feat + (size_t)b * D_K;          sq = sq_a + b; }
    else         { src = lut + (size_t)(b - B_N) * D_K;   sq = sq_b + (b - B_N); }

    float4 v = ((const float4*)src)[t];        // k = 4t .. 4t+3
    float ss = v.x * v.x + v.y * v.y + v.z * v.z + v.w * v.w;
    ushort4 bb;
    bb.x = f2bf(v.x); bb.y = f2bf(v.y); bb.z = f2bf(v.z); bb.w = f2bf(v.w);

    if (b < B_N) {
        // packed: kt = t>>3, h = (t>>1)&3, e0 = (t&1)*4
        int g = b >> 4, rl = b & 15;
        int kt = t >> 3, h = (t >> 1) & 3, e0 = (t & 1) * 4;
        size_t off = ((size_t)g * 32 + kt) * 512 + (rl + h * 16) * 8 + e0;
        *(ushort4*)(featP + off) = bb;
    } else {
        ((ushort4*)(lutB + (size_t)(b - B_N) * D_K))[t] = bb;
    }

    int lane = t & 63, w = t >> 6;
    #pragma unroll
    for (int o = 1; o < 64; o <<= 1) ss += __shfl_xor(ss, o);
    __shared__ float red[4];
    if (lane == 0) red[w] = ss;
    __syncthreads();
    if (t == 0) *sq = red[0] + red[1] + red[2] + red[3];
}

// 128x64-tile bf16 MFMA GEMM over D = feat x lut[0:1024]^T (M=4096, N=1024,
// K=1024). Split operand paths, DMA minimized:
//   A: register-direct from packed panels (1 coalesced 16B/lane load per
//      frag, wave-exclusive rows -> no LDS, no barriers, no duplication)
//   B: global_load_lds into 8 KB double-buffered LDS (shared by all 4
//      waves), zero-conflict row-pair XOR swizzle (verified R7/R8/R10/R12),
//      counted vmcnt(5) = {A(kt)x2, B(kt+1), A(kt+1)x2} newer than B(kt).
// 4 waves, each 32 rows x 64 cols (2 A-frags x 4 B-frags, 8 MFMA/kt).
// Grid 512 blocks = 2/CU.
__global__ __launch_bounds__(256, 4)
void dist_kernel(const ushort* __restrict__ Ap, const ushort* __restrict__ Bm,
                 const float* __restrict__ sqa, const float* __restrict__ sqb,
                 const int* __restrict__ ids, const int* __restrict__ cnt,
                 int* __restrict__ maxb, int* __restrict__ minb) {
    __shared__ __align__(16) ushort lB[2][2048];   // 8 KB total

    const int t = threadIdx.x;
    const int lane = t & 63;
    const int wid = t >> 6;          // 4 waves = 4 row-bands of 32
    const int l15 = lane & 15;
    const int h = lane >> 4;

    // T1 XCD swizzle: 512 blocks -> XCD k owns row-tiles 4k..4k+3 x all 16
    // col-tiles (A panels 1 MB + B 2 MB < 4 MB L2).
    const int bid = blockIdx.y * gridDim.x + blockIdx.x;   // gridDim.x = 16
    const int swz = (bid & 7) * 64 + (bid >> 3);
    const int rb = swz >> 4, cb = swz & 15;    // rb 0..31, cb 0..15

    // ---- B staging source (row-pair XOR swizzle, as R12): 64x32 tile =
    // 2048 elems. Phys elem p = t*8; line rp = p>>6; slot' = (p>>3)&7;
    // sl = slot' ^ (rp&7); row = rp*2 + (sl>>2); chunk j = sl&3.
    int p = t * 8;
    int rp = p >> 6;
    int sl = ((p >> 3) & 7) ^ (rp & 7);
    int rr = rp * 2 + (sl >> 2);
    int jj = sl & 3;
    const ushort* gB = Bm + (size_t)(cb * 64 + rr) * D_K + jj * 8;
    const int wo = wid * 512;        // per-wave LDS staging offset (elems)

    // ---- swizzled B fragment read offsets (rows nf*16 + l15)
    const int par = (l15 & 1) << 2;
    int offB[4];
    #pragma unroll
    for (int nf = 0; nf < 4; nf++) {
        int line = (l15 >> 1) + nf * 8;
        offB[nf] = line * 64 + (((par | h) ^ (line & 7)) << 3);
    }

    // ---- A packed-panel pointers (groups of 16 rows; wave-exclusive)
    const ushort* pa0 = Ap + ((size_t)(rb * 8 + wid * 2 + 0) * 32) * 512 + lane * 8;
    const ushort* pa1 = Ap + ((size_t)(rb * 8 + wid * 2 + 1) * 32) * 512 + lane * 8;

    f32x4 acc[2][4] = {};
    short8 aE0, aE1, aO0, aO1, bfv[4];

    // ---- prologue: B(0) DMA + A(0) reg loads
    async16(gB, &lB[0][0] + wo);
    aE0 = *(const short8*)(pa0);
    aE1 = *(const short8*)(pa1);

#define MFMA16(av0, av1)                                                    \
    _Pragma("unroll") for (int nf = 0; nf < 4; nf++) {                      \
        acc[0][nf] = __builtin_amdgcn_mfma_f32_16x16x32_bf16(               \
            av0, bfv[nf], acc[0][nf], 0, 0, 0);                             \
        acc[1][nf] = __builtin_amdgcn_mfma_f32_16x16x32_bf16(               \
            av1, bfv[nf], acc[1][nf], 0, 0, 0);                             \
    }

#define ITER(KT, C0, C1, N0, N1)                                            \
    {                                                                       \
        const int s_ = (KT) & 1;                                            \
        if ((KT) < 31) {                                                    \
            async16(gB + ((KT) + 1) * 32, &lB[s_ ^ 1][0] + wo);             \
            N0 = *(const short8*)(pa0 + ((KT) + 1) * 512);                  \
            N1 = *(const short8*)(pa1 + ((KT) + 1) * 512);                  \
            __builtin_amdgcn_sched_barrier(0);                              \
            asm volatile("s_waitcnt vmcnt(5)" ::: "memory");                \
        } else {                                                            \
            asm volatile("s_waitcnt vmcnt(0)" ::: "memory");                \
        }                                                                   \
        __builtin_amdgcn_sched_barrier(0);                                  \
        __builtin_amdgcn_s_barrier();      /* RAW: B(kt) visible */         \
        __builtin_amdgcn_sched_barrier(0);                                  \
        _Pragma("unroll") for (int nf = 0; nf < 4; nf++)                    \
            bfv[nf] = *(const short8*)(&lB[s_][0] + offB[nf]);              \
        MFMA16(C0, C1);                                                     \
        __builtin_amdgcn_sched_barrier(0);                                  \
        __builtin_amdgcn_s_barrier();      /* WAR: B reads done */          \
    }

    for (int kt = 0; kt < 32; kt += 2) {
        ITER(kt,     aE0, aE1, aO0, aO1);
        ITER(kt + 1, aO0, aO1, aE0, aE1);
    }
#undef ITER
#undef MFMA16

    // Epilogue: col c IS the id. pos = (c==ida && cnt[c]>=2);
    // neg = (cnt[c]>0 && c!=ida). Per-row max/min over this block's 64 cols.
    int colg[4]; float sb2[4]; int c2[4];
    #pragma unroll
    for (int nf = 0; nf < 4; nf++) {
        int c = cb * 64 + nf * 16 + l15;
        colg[nf] = c; sb2[nf] = sqb[c]; c2[nf] = cnt[c];
    }
    #pragma unroll
    for (int m = 0; m < 2; m++) {
        #pragma unroll
        for (int r = 0; r < 4; r++) {
            int row = rb * 128 + wid * 32 + m * 16 + h * 4 + r;
            float sa = sqa[row];
            int ida = ids[row];
            float mx = 0.0f, mn = 3.0e38f;
            #pragma unroll
            for (int nf = 0; nf < 4; nf++) {
                float s2 = sa + sb2[nf] - 2.0f * acc[m][nf][r];
                float d = sqrtf(fmaxf(s2, 0.0f) + 1e-12f);
                bool iseq = (colg[nf] == ida);
                float pv = (iseq && c2[nf] >= 2) ? d : 0.0f;
                float nv = (c2[nf] > 0 && !iseq) ? d : 3.0e38f;
                mx = fmaxf(mx, pv);
                mn = fminf(mn, nv);
            }
            #pragma unroll
            for (int o = 1; o < 16; o <<= 1) {
                mx = fmaxf(mx, __shfl_xor(mx, o));
                mn = fminf(mn, __shfl_xor(mn, o));
            }
            if (l15 == 0) {
                atomicMax(maxb + row, __float_as_int(mx));
                atomicMin(minb + row, __float_as_int(mn));
            }
        }
    }
}

__global__ void finalize_k(const int* __restrict__ maxb, const int* __restrict__ minb,
                           float* __restrict__ out) {
    int i = blockIdx.x * blockDim.x + threadIdx.x;
    if (i < B_N) {
        float z = __int_as_float(maxb[i]) - __int_as_float(minb[i]) + MARGIN;
        out[i] = fmaxf(z, 0.0f);
    }
}

extern "C" void kernel_launch(void* const* d_in, const int* in_sizes, int n_in,
                              void* d_out, int out_size, void* d_ws, size_t ws_size,
                              hipStream_t stream) {
    const float* feat = (const float*)d_in[0];
    const float* lut  = (const float*)d_in[1];
    const int*   id   = (const int*)d_in[2];
    float* out = (float*)d_out;

    // workspace layout
    char* ws = (char*)d_ws;
    ushort* featP = (ushort*)ws;                                   // 8 MiB packed
    ushort* lutB  = (ushort*)(ws + (size_t)B_N * D_K * 2);         // 2 MiB
    float*  sq_a  = (float*)(ws + (size_t)(B_N + N_C) * D_K * 2);
    float*  sq_b  = sq_a + B_N;
    int*    cnt   = (int*)(sq_b + N_C);
    int*    maxb  = cnt + N_C;
    int*    minb  = maxb + B_N;

    prep_all<<<B_N + N_C + 1, 256, 0, stream>>>(feat, lut, id, featP, lutB,
                                                sq_a, sq_b, cnt, maxb, minb);

    dim3 grid(N_C / 64, B_N / 128);    // 16 x 32 = 512 blocks
    dist_kernel<<<grid, 256, 0, stream>>>(featP, lutB, sq_a, sq_b, id, cnt,
                                          maxb, minb);

    finalize_k<<<16, 256, 0, stream>>>(maxb, minb, out);
}